// Round 8
// baseline (129.629 us; speedup 1.0000x reference)
//
#include <hip/hip_runtime.h>

// IDWT3D (haar, tiny): out[T,H,W,c] = x[T/2,H/2,W/2,c] * (1/sqrt2)^3
// x: (16,128,128,64) f32 -> out: (32,256,256,64) f32
//
// R8: A/B on store cache policy. Identical to R4 (the best structure:
// grid-stride, 1 input f4 -> 8 scatter stores, temporal loads) but with
// PLAIN stores instead of nontemporal. Hypothesis: the harness memset
// sustains 6.7 TB/s via the L2 write-combining path (write-allocate,
// full-line bursts to HBM); nt stores bypass it and pay ~10% burst
// efficiency. Risk case: 512 MiB write stream thrashes memory-side L3
// and evicts the 64 MiB input -> +64 MiB HBM read per replay.
//
// Output f4 index (T,H,W,c4) = (T<<20) + (H<<12) + (W<<4) + c4
// Input  f4 index (t,h,w,c4) = (t<<18) + (h<<11) + (w<<4) + c4

typedef float f4 __attribute__((ext_vector_type(4)));

__global__ void idwt3_haar_scatter(const f4* __restrict__ in,
                                   f4* __restrict__ out,
                                   int nin4) {
    const float s = 0.35355339059327379f;  // (1/sqrt2)^3
    int idx = blockIdx.x * blockDim.x + threadIdx.x;
    int stride = gridDim.x * blockDim.x;
    for (int v = idx; v < nin4; v += stride) {
        int c4 = v & 15;
        int w  = (v >> 4) & 127;
        int h  = (v >> 11) & 127;
        int t  = v >> 18;
        f4 x = in[v];          // temporal: L3-resident across replays
        x *= s;
        int base = (t << 21) + (h << 13) + (w << 5) + c4;
        f4* p0 = out + base;                         // (2t,   2h,   2w)
        f4* p1 = out + base + (1 << 12);             // (2t,   2h+1, 2w)
        f4* p2 = out + base + (1 << 20);             // (2t+1, 2h,   2w)
        f4* p3 = out + base + (1 << 20) + (1 << 12); // (2t+1, 2h+1, 2w)
        p0[0]  = x;
        p0[16] = x;            // W+1
        p1[0]  = x;
        p1[16] = x;
        p2[0]  = x;
        p2[16] = x;
        p3[0]  = x;
        p3[16] = x;
    }
}

extern "C" void kernel_launch(void* const* d_in, const int* in_sizes, int n_in,
                              void* d_out, int out_size, void* d_ws, size_t ws_size,
                              hipStream_t stream) {
    const f4* in = (const f4*)d_in[0];
    f4* out = (f4*)d_out;
    int nin4 = in_sizes[0] / 4;  // 4,194,304 input float4
    int block = 256;
    int grid = 2048;             // grid-stride, 8 iters/thread
    idwt3_haar_scatter<<<grid, block, 0, stream>>>(in, out, nin4);
}

// Round 9
// 92.603 us; speedup vs baseline: 1.3998x; 1.3998x over previous
//
#include <hip/hip_runtime.h>

// IDWT3D (haar, tiny): out[T,H,W,c] = x[T/2,H/2,W/2,c] * (1/sqrt2)^3
// x: (16,128,128,64) f32 -> out: (32,256,256,64) f32
//
// FINAL (= R4, the measured optimum at 92.7 us = 5.8 TB/s write BW, ~86-90%
// of the memset-observed write ceiling). Gather->scatter: each thread loads
// ONE input float4 (temporal -> 64 MiB input stays L3-resident across graph
// replays; steady-state HBM traffic is write-only) and writes its 8 upsample
// duplicates with NONTEMPORAL stores (write-once 512 MiB; no L2/L3
// write-allocate, so the input is never evicted -- R8 proved plain stores
// cost +40%).
//
// Tested-and-rejected variants: wave-contiguous stores (R5, +15%), batched
// unrolled loads (R6, +5%), SGPR-base/32-bit-offset addressing (R7, +7%),
// plain stores (R8, +40%). The simple grid-stride 8-scatter loop wins.
//
// Output f4 index (T,H,W,c4) = (T<<20) + (H<<12) + (W<<4) + c4
// Input  f4 index (t,h,w,c4) = (t<<18) + (h<<11) + (w<<4) + c4

typedef float f4 __attribute__((ext_vector_type(4)));

__global__ void idwt3_haar_scatter(const f4* __restrict__ in,
                                   f4* __restrict__ out,
                                   int nin4) {
    const float s = 0.35355339059327379f;  // (1/sqrt2)^3
    int idx = blockIdx.x * blockDim.x + threadIdx.x;
    int stride = gridDim.x * blockDim.x;
    for (int v = idx; v < nin4; v += stride) {
        int c4 = v & 15;
        int w  = (v >> 4) & 127;
        int h  = (v >> 11) & 127;
        int t  = v >> 18;
        f4 x = in[v];          // temporal: L3-resident across replays
        x *= s;
        int base = (t << 21) + (h << 13) + (w << 5) + c4;
        f4* p0 = out + base;                         // (2t,   2h,   2w)
        f4* p1 = out + base + (1 << 12);             // (2t,   2h+1, 2w)
        f4* p2 = out + base + (1 << 20);             // (2t+1, 2h,   2w)
        f4* p3 = out + base + (1 << 20) + (1 << 12); // (2t+1, 2h+1, 2w)
        __builtin_nontemporal_store(x, p0);
        __builtin_nontemporal_store(x, p0 + 16);     // W+1
        __builtin_nontemporal_store(x, p1);
        __builtin_nontemporal_store(x, p1 + 16);
        __builtin_nontemporal_store(x, p2);
        __builtin_nontemporal_store(x, p2 + 16);
        __builtin_nontemporal_store(x, p3);
        __builtin_nontemporal_store(x, p3 + 16);
    }
}

extern "C" void kernel_launch(void* const* d_in, const int* in_sizes, int n_in,
                              void* d_out, int out_size, void* d_ws, size_t ws_size,
                              hipStream_t stream) {
    const f4* in = (const f4*)d_in[0];
    f4* out = (f4*)d_out;
    int nin4 = in_sizes[0] / 4;  // 4,194,304 input float4
    int block = 256;
    int grid = 2048;             // grid-stride, 8 iters/thread
    idwt3_haar_scatter<<<grid, block, 0, stream>>>(in, out, nin4);
}